// Round 1
// baseline (45.281 us; speedup 1.0000x reference)
//
#include <hip/hip_runtime.h>

// RightPool: out[b,c,h,w] = max(x[b,c,h,0..w])  — cummax along last (contiguous) axis, W=128.
// One 32-lane group per row: float4 per lane (512B/row coalesced), local 4-elem scan +
// 5-step shfl_up segmented scan (width=32), then combine with exclusive prefix.

__global__ void rightpool_kernel(const float* __restrict__ x,
                                 float* __restrict__ out,
                                 int nrows) {
    const int tid      = blockIdx.x * blockDim.x + threadIdx.x;
    const int nthreads = gridDim.x * blockDim.x;
    const int lane32   = threadIdx.x & 31;
    const int ngroups  = nthreads >> 5;

    for (int row = tid >> 5; row < nrows; row += ngroups) {
        const float4* px = reinterpret_cast<const float4*>(x + (size_t)row * 128) + lane32;
        float4 v = *px;

        // local inclusive scan over the 4 elements
        float y0 = v.x;
        float y1 = fmaxf(y0, v.y);
        float y2 = fmaxf(y1, v.z);
        float y3 = fmaxf(y2, v.w);

        // inclusive scan of lane maxes across the 32-lane segment
        float m = y3;
        #pragma unroll
        for (int d = 1; d < 32; d <<= 1) {
            float t = __shfl_up(m, d, 32);
            if (lane32 >= d) m = fmaxf(m, t);
        }
        // exclusive prefix for this lane
        float ex = __shfl_up(m, 1, 32);
        if (lane32 == 0) ex = -__builtin_inff();

        float4 o;
        o.x = fmaxf(ex, y0);
        o.y = fmaxf(ex, y1);
        o.z = fmaxf(ex, y2);
        o.w = fmaxf(ex, y3);
        *(reinterpret_cast<float4*>(out + (size_t)row * 128) + lane32) = o;
    }
}

extern "C" void kernel_launch(void* const* d_in, const int* in_sizes, int n_in,
                              void* d_out, int out_size, void* d_ws, size_t ws_size,
                              hipStream_t stream) {
    const float* x = (const float*)d_in[0];
    float* out     = (float*)d_out;

    const int W     = 128;
    const int nrows = out_size / W;  // 8*256*128 = 262144

    const int block = 256;
    // memory-bound: cap grid at ~8 blocks/CU and grid-stride the rest
    int total_groups_needed = nrows;                       // one 32-lane group per row
    int blocks_needed = (total_groups_needed * 32 + block - 1) / block;
    int blocks = blocks_needed < 2048 ? blocks_needed : 2048;

    rightpool_kernel<<<blocks, block, 0, stream>>>(x, out, nrows);
}